// Round 2
// baseline (427.945 us; speedup 1.0000x reference)
//
#include <hip/hip_runtime.h>
#include <hip/hip_bf16.h>

#define M 2048
#define N 131072
#define D 256

#define SLICE_G 64                     // n-groups (of 16) per slice = 1024 n
#define NSLICE  (N / (SLICE_G * 16))   // 128
#define BIAS    1024.0f                // score = vsq+BIAS-2qv > 0 -> uint-sortable bits

typedef __attribute__((ext_vector_type(8))) _Float16 half8;  // 8 f16 (4 VGPRs)
typedef __attribute__((ext_vector_type(8))) short short8;
typedef __attribute__((ext_vector_type(4))) float f32x4;     // MFMA acc
typedef unsigned long long ull;

__device__ __forceinline__ ull pack_key(float score, unsigned idx) {
    unsigned u = __float_as_uint(score);
    u = (u & 0x80000000u) ? ~u : (u | 0x80000000u);
    return ((ull)u << 32) | idx;
}

// async 16B global -> LDS (wave-uniform LDS base; HW adds lane*16; global addr per-lane)
__device__ __forceinline__ void gload_lds16(const void* g, void* l) {
    __builtin_amdgcn_global_load_lds(
        (const __attribute__((address_space(1))) void*)g,
        (__attribute__((address_space(3))) void*)l, 16, 0, 0);
}

// ---------------- Kernel A: q -> f16 frag-linear (tiny: 128 blocks) + keys init -------
__global__ __launch_bounds__(256) void q_convert(const float* __restrict__ q,
                                                 short* __restrict__ qf,
                                                 ull* __restrict__ keys) {
    const int g    = blockIdx.x;
    const int t    = threadIdx.x;
    const int w    = t >> 6;
    const int l    = t & 63;
    const int quad = (l >> 4) & 3;
    const int tx   = l & 15;

    const float* src = q + (size_t)g * 4096;
#pragma unroll
    for (int h = 0; h < 2; ++h) {
        const int c = w + h * 4;
        const float* p = src + tx * 256 + c * 32 + quad * 8;   // contiguous 32B/lane
        const float4 f0 = *(const float4*)p;
        const float4 f1 = *(const float4*)(p + 4);
        half8 hh;
        hh[0] = (_Float16)f0.x; hh[1] = (_Float16)f0.y;
        hh[2] = (_Float16)f0.z; hh[3] = (_Float16)f0.w;
        hh[4] = (_Float16)f1.x; hh[5] = (_Float16)f1.y;
        hh[6] = (_Float16)f1.z; hh[7] = (_Float16)f1.w;
        *(short8*)(qf + ((size_t)g * 8 + c) * 512 + l * 8) = *(short8*)&hh;
    }
    if (g == 0)
        for (int i = t; i < 2 * M; i += 256) keys[i] = ~0ull;
}

// ---------------- Kernel B: FUSED — stages fp32 v, cvt+vsq on the fly, MFMA argmin ----
// Eliminates the 196MB convert round-trip. Per g-tile (16 rows x 256 f32 = 16KB,
// contiguous in v): async-stage with a per-lane-swizzled SOURCE address so the linear
// LDS image is granule-XOR-swizzled per row (granule col ^ (row&7)) -> the frag-order
// ds_read_b128 (16 tx lanes reading different rows, same col) is 2-way conflict = free
// instead of 16-way. Each wave cvt's its B-frags f32->f16 in regs and accumulates
// vsq from the same values (split fmac chains + 2 shfl_xor), replacing vsqb.
__global__ __launch_bounds__(256, 2) void dist_argmin_fused(const short* __restrict__ qf,
                                                            const float* __restrict__ v,
                                                            ull* __restrict__ keys1,
                                                            ull* __restrict__ keys2) {
    __shared__ float bt[2][16 * 256];      // 2 x 16KB fp32 tile double buffer

    const int tid  = threadIdx.x;
    const int lane = tid & 63;
    const int w    = tid >> 6;
    const int tx   = lane & 15;
    const int quad = (lane >> 4) & 3;

    // XCD swizzle: 1024 blocks; lb%8 = XCD; each XCD covers its own 16 slices
    const int lb    = blockIdx.x;
    const int xcd   = lb & 7;
    const int s_    = lb >> 3;              // 0..127 within XCD
    const int slice = xcd * 16 + (s_ >> 3);
    const int qblk  = s_ & 7;

    const int qb0 = qblk * 256 + w * 64;    // wave's first q-row (64 rows)
    const int sg0 = slice * SLICE_G;

    half8 aq[4][8];                         // 128 regs, loaded once
#pragma unroll
    for (int mt = 0; mt < 4; ++mt)
#pragma unroll
        for (int c = 0; c < 8; ++c)
            aq[mt][c] = *(const half8*)(qf + ((size_t)((qb0 >> 4) + mt) * 8 + c) * 512 + lane * 8);

    unsigned best[16];
#pragma unroll
    for (int i = 0; i < 16; ++i) best[i] = 0xFFFFFFFFu;

    const float* vbase = v + (size_t)sg0 * 16 * 256;   // slice base (fp32 rows)

    // stage g-tile: 16 rows x 1KB; row i -> LDS row i linear, source granule lane^(i&7)
    auto stage = [&](float* buf, int g) {
        const float* gsrc = vbase + (size_t)g * 4096;
#pragma unroll
        for (int i = 0; i < 4; ++i) {
            const int row = w * 4 + i;                          // wave-uniform
            gload_lds16(gsrc + row * 256 + ((lane ^ (row & 7)) << 2), buf + row * 256);
        }
    };

    auto compute = [&](const float* buf, int g) {
        f32x4 acc[4];
#pragma unroll
        for (int i = 0; i < 4; ++i) acc[i] = (f32x4){0.f, 0.f, 0.f, 0.f};
        float vs0 = 0.f, vs1 = 0.f, vs2 = 0.f, vs3 = 0.f;
#pragma unroll
        for (int c = 0; c < 8; ++c) {
            const int gc = c * 8 + quad * 2;                    // 16B-granule col
            const float4 f0 = *(const float4*)&buf[tx * 256 + ((gc ^ (tx & 7)) << 2)];
            const float4 f1 = *(const float4*)&buf[tx * 256 + (((gc + 1) ^ (tx & 7)) << 2)];
            vs0 = fmaf(f0.x, f0.x, vs0); vs1 = fmaf(f0.y, f0.y, vs1);
            vs2 = fmaf(f0.z, f0.z, vs2); vs3 = fmaf(f0.w, f0.w, vs3);
            vs0 = fmaf(f1.x, f1.x, vs0); vs1 = fmaf(f1.y, f1.y, vs1);
            vs2 = fmaf(f1.z, f1.z, vs2); vs3 = fmaf(f1.w, f1.w, vs3);
            half8 b;
            b[0] = (_Float16)f0.x; b[1] = (_Float16)f0.y;
            b[2] = (_Float16)f0.z; b[3] = (_Float16)f0.w;
            b[4] = (_Float16)f1.x; b[5] = (_Float16)f1.y;
            b[6] = (_Float16)f1.z; b[7] = (_Float16)f1.w;
#pragma unroll
            for (int mt = 0; mt < 4; ++mt)
                acc[mt] = __builtin_amdgcn_mfma_f32_16x16x32_f16(aq[mt][c], b, acc[mt], 0, 0, 0);
        }
        float vs = (vs0 + vs1) + (vs2 + vs3);  // lane: partial sumsq of row tx (its quad's k)
        vs += __shfl_xor(vs, 16, 64);
        vs += __shfl_xor(vs, 32, 64);          // full ||v_(tx)||^2 in every lane
        const float vsqr = vs + BIAS;
#pragma unroll
        for (int mt = 0; mt < 4; ++mt)
#pragma unroll
            for (int r = 0; r < 4; ++r) {
                const float sc = fmaf(-2.f, acc[mt][r], vsqr);
                const unsigned key = (__float_as_uint(sc) & 0xFFFFFFC0u) | (unsigned)g;
                const int sl = mt * 4 + r;
                best[sl] = key < best[sl] ? key : best[sl];
            }
    };

    stage(bt[0], 0);
    __syncthreads();                        // drains vmcnt(0): buf0 ready

    for (int g = 0; g < SLICE_G; g += 2) {
        stage(bt[1], g + 1);                // prefetch next tile (async, no VGPR dest)
        compute(bt[0], g);
        __syncthreads();                    // tile g+1 landed; all reads of bt[0] done
        if (g + 2 < SLICE_G) stage(bt[0], g + 2);
        compute(bt[1], g + 1);
        __syncthreads();
    }

    // Epilogue: per slot, min across 16 tx lanes; recover (g, tx); top-2 insert.
#pragma unroll
    for (int mt = 0; mt < 4; ++mt)
#pragma unroll
        for (int r = 0; r < 4; ++r) {
            const int sl = mt * 4 + r;
            unsigned k = best[sl];
#pragma unroll
            for (int off = 8; off; off >>= 1) {
                const unsigned o = (unsigned)__shfl_xor((int)k, off, 16);
                k = o < k ? o : k;
            }
            const ull bal = __ballot(best[sl] == k);
            const unsigned grp = (unsigned)((bal >> (quad * 16)) & 0xFFFFull);
            const int wtx = __ffs((int)grp) - 1;
            const unsigned n = (unsigned)((sg0 + (int)(k & 63u)) * 16 + wtx);
            if (tx == 0) {
                const int row = qb0 + mt * 16 + quad * 4 + r;
                const ull key64 = ((ull)k << 32) | n;
                const ull old = atomicMin(&keys1[row], key64);
                const ull loser = (key64 < old) ? old : key64;
                if (loser != ~0ull) atomicMin(&keys2[row], loser);
            }
        }
}

// ---------------- Kernel C: exact fp32 rescore of approx top-2 ----------------
__global__ __launch_bounds__(256) void rescore_kernel(const float* __restrict__ q,
                                                      const float* __restrict__ v,
                                                      const ull* __restrict__ keys1,
                                                      const ull* __restrict__ keys2,
                                                      int* __restrict__ out) {
    const int qi   = blockIdx.x * 4 + (threadIdx.x >> 6);
    const int lane = threadIdx.x & 63;
    const float4 qv = *(const float4*)(q + (size_t)qi * D + lane * 4);
    ull best = ~0ull;
    ull cand[2];
    cand[0] = keys1[qi];
    cand[1] = keys2[qi];
#pragma unroll
    for (int c = 0; c < 2; ++c) {
        if (cand[c] == ~0ull) continue;
        const unsigned idx = (unsigned)cand[c];
        const float4 vv = *(const float4*)(v + (size_t)idx * D + lane * 4);
        float s1 = vv.x * vv.x + vv.y * vv.y + vv.z * vv.z + vv.w * vv.w;   // ||v||^2
        float s2 = qv.x * vv.x + qv.y * vv.y + qv.z * vv.z + qv.w * vv.w;   // q.v
#pragma unroll
        for (int off = 32; off; off >>= 1) {
            s1 += __shfl_xor(s1, off, 64);
            s2 += __shfl_xor(s2, off, 64);
        }
        const float dist = fmaf(-2.0f, s2, s1);   // exact fp32 (sans ||q||^2)
        const ull key = pack_key(dist, idx);
        best = best < key ? best : key;
    }
    if (lane == 0) out[qi] = (int)(unsigned)(best & 0xFFFFFFFFull);
}

extern "C" void kernel_launch(void* const* d_in, const int* in_sizes, int n_in,
                              void* d_out, int out_size, void* d_ws, size_t ws_size,
                              hipStream_t stream) {
    const float* q = (const float*)d_in[0];
    const float* v = (const float*)d_in[1];
    int* out = (int*)d_out;

    char* ws = (char*)d_ws;
    ull* keys1 = (ull*)ws;                   ws += (size_t)2 * M * sizeof(ull);
    ull* keys2 = keys1 + M;
    short* qf = (short*)ws;                  // 1 MB frag-linear q

    q_convert<<<M / 16, 256, 0, stream>>>(q, qf, keys1);

    dist_argmin_fused<<<(M / 256) * NSLICE, 256, 0, stream>>>(qf, v, keys1, keys2);

    rescore_kernel<<<M / 4, 256, 0, stream>>>(q, v, keys1, keys2, out);
}

// Round 3
// 392.155 us; speedup vs baseline: 1.0913x; 1.0913x over previous
//
#include <hip/hip_runtime.h>
#include <hip/hip_bf16.h>

#define M 2048
#define N 131072
#define D 256

#define SLICE_G 64                     // n-groups (of 16) per slice = 1024 n
#define NSLICE  (N / (SLICE_G * 16))   // 128
#define BIAS    1024.0f                // score = vsq+BIAS-2qv > 0 -> uint-sortable bits

typedef __attribute__((ext_vector_type(8))) _Float16 half8;  // 8 f16 (4 VGPRs)
typedef __attribute__((ext_vector_type(8))) short short8;
typedef __attribute__((ext_vector_type(4))) float f32x4;     // MFMA acc
typedef unsigned long long ull;

__device__ __forceinline__ ull pack_key(float score, unsigned idx) {
    unsigned u = __float_as_uint(score);
    u = (u & 0x80000000u) ? ~u : (u | 0x80000000u);
    return ((ull)u << 32) | idx;
}

// ---------------- Kernel B (the only big kernel): FULLY FUSED ----------------
// No converter kernels, no vf/qf workspace (reset()-repoison of 65MB ws was ~60us/iter).
// A-frags: gathered direct from fp32 q (L2-hot), cvt in regs (once per block).
// B-tiles: per g, reg-stage fp32 (4 float4/lane), cvt to f16 in regs, ds_write
// frag-linear (64 lanes x 16B contiguous per chunk -> conflict-free), then all waves
// ds_read f16 frags (lane*16 linear, R1-proven 0 conflicts). T14 split: loads for g+1
// issue BEFORE compute(g); cvt+ds_write after; ONE barrier per tile.
// vsq: fp32 sumsq from the staged regs (16 fmaf + 2 shfl), 4 wave-partials in LDS.
__global__ __launch_bounds__(256, 2) void dist_argmin_fused(const float* __restrict__ q,
                                                            const float* __restrict__ v,
                                                            ull* __restrict__ keys1,
                                                            ull* __restrict__ keys2) {
    __shared__ short bt[2][8 * 512];       // f16 frag-linear tile, 8KB x 2
    __shared__ float vsq_s[2][4][16];      // per-buffer, per-wave row-sumsq partials

    const int tid  = threadIdx.x;
    const int lane = tid & 63;
    const int w    = tid >> 6;
    const int tx   = lane & 15;
    const int quad = (lane >> 4) & 3;

    // XCD swizzle: 1024 blocks; lb%8 = XCD; each XCD covers its own 16 slices
    const int lb    = blockIdx.x;
    const int xcd   = lb & 7;
    const int s_    = lb >> 3;              // 0..127 within XCD
    const int slice = xcd * 16 + (s_ >> 3);
    const int qblk  = s_ & 7;

    const int qb0 = qblk * 256 + w * 64;    // wave's first q-row (64 rows)
    const int sg0 = slice * SLICE_G;

    // Prologue: A-frags direct from fp32 q, cvt in regs (128 regs)
    half8 aq[4][8];
#pragma unroll
    for (int mt = 0; mt < 4; ++mt) {
        const float* qrow = q + (size_t)(qb0 + mt * 16 + tx) * 256 + quad * 8;
#pragma unroll
        for (int c = 0; c < 8; ++c) {
            const float4 f0 = *(const float4*)(qrow + c * 32);
            const float4 f1 = *(const float4*)(qrow + c * 32 + 4);
            half8 hh;
            hh[0] = (_Float16)f0.x; hh[1] = (_Float16)f0.y;
            hh[2] = (_Float16)f0.z; hh[3] = (_Float16)f0.w;
            hh[4] = (_Float16)f1.x; hh[5] = (_Float16)f1.y;
            hh[6] = (_Float16)f1.z; hh[7] = (_Float16)f1.w;
            aq[mt][c] = hh;
        }
    }

    unsigned best[16];
#pragma unroll
    for (int i = 0; i < 16; ++i) best[i] = 0xFFFFFFFFu;

    // wave stages chunks c0=w, c1=w+4 of each tile; lane covers row tx, k=c*32+quad*8..+7
    const int c0 = w, c1 = w + 4;
    const float* vtile = v + ((size_t)sg0 * 16 + tx) * 256 + quad * 8;

    float4 s00, s01, s10, s11;              // staged fp32 for next tile (16 VGPR, T14)

    auto stage_load = [&](int g) {
        const float* p = vtile + (size_t)g * 4096;
        s00 = *(const float4*)(p + c0 * 32);
        s01 = *(const float4*)(p + c0 * 32 + 4);
        s10 = *(const float4*)(p + c1 * 32);
        s11 = *(const float4*)(p + c1 * 32 + 4);
    };
    auto stage_store = [&](int pb) {
        float s = s00.x * s00.x + s00.y * s00.y + s00.z * s00.z + s00.w * s00.w;
        s = fmaf(s01.x, s01.x, s); s = fmaf(s01.y, s01.y, s);
        s = fmaf(s01.z, s01.z, s); s = fmaf(s01.w, s01.w, s);
        s = fmaf(s10.x, s10.x, s); s = fmaf(s10.y, s10.y, s);
        s = fmaf(s10.z, s10.z, s); s = fmaf(s10.w, s10.w, s);
        s = fmaf(s11.x, s11.x, s); s = fmaf(s11.y, s11.y, s);
        s = fmaf(s11.z, s11.z, s); s = fmaf(s11.w, s11.w, s);
        half8 h0, h1;
        h0[0] = (_Float16)s00.x; h0[1] = (_Float16)s00.y;
        h0[2] = (_Float16)s00.z; h0[3] = (_Float16)s00.w;
        h0[4] = (_Float16)s01.x; h0[5] = (_Float16)s01.y;
        h0[6] = (_Float16)s01.z; h0[7] = (_Float16)s01.w;
        h1[0] = (_Float16)s10.x; h1[1] = (_Float16)s10.y;
        h1[2] = (_Float16)s10.z; h1[3] = (_Float16)s10.w;
        h1[4] = (_Float16)s11.x; h1[5] = (_Float16)s11.y;
        h1[6] = (_Float16)s11.z; h1[7] = (_Float16)s11.w;
        *(short8*)&bt[pb][c0 * 512 + lane * 8] = *(short8*)&h0;   // linear 1KB, no conflicts
        *(short8*)&bt[pb][c1 * 512 + lane * 8] = *(short8*)&h1;
        s += __shfl_xor(s, 16, 64);
        s += __shfl_xor(s, 32, 64);          // row-tx sumsq over this wave's 2 chunks
        if (lane < 16) vsq_s[pb][w][lane] = s;
    };

    auto compute = [&](int pb, int g) {
        const float vsqr = vsq_s[pb][0][tx] + vsq_s[pb][1][tx]
                         + vsq_s[pb][2][tx] + vsq_s[pb][3][tx] + BIAS;
        f32x4 acc[4];
#pragma unroll
        for (int i = 0; i < 4; ++i) acc[i] = (f32x4){0.f, 0.f, 0.f, 0.f};
        __builtin_amdgcn_s_setprio(1);
#pragma unroll
        for (int c = 0; c < 8; ++c) {
            const half8 b = *(const half8*)&bt[pb][c * 512 + lane * 8];
#pragma unroll
            for (int mt = 0; mt < 4; ++mt)
                acc[mt] = __builtin_amdgcn_mfma_f32_16x16x32_f16(aq[mt][c], b, acc[mt], 0, 0, 0);
        }
        __builtin_amdgcn_s_setprio(0);
#pragma unroll
        for (int mt = 0; mt < 4; ++mt)
#pragma unroll
            for (int r = 0; r < 4; ++r) {
                const float sc = fmaf(-2.f, acc[mt][r], vsqr);
                const unsigned key = (__float_as_uint(sc) & 0xFFFFFFC0u) | (unsigned)g;
                const int sl = mt * 4 + r;
                best[sl] = key < best[sl] ? key : best[sl];
            }
    };

    stage_load(0);
    stage_store(0);
    __syncthreads();                        // buf0 published

    int pb = 0;
    for (int g = 0; g < SLICE_G; ++g) {
        if (g + 1 < SLICE_G) stage_load(g + 1);   // issue early: hides under compute
        compute(pb, g);
        if (g + 1 < SLICE_G) stage_store(pb ^ 1); // cvt + ds_write after compute
        __syncthreads();                          // one barrier per tile
        pb ^= 1;
    }

    // Epilogue: per slot, min across 16 tx lanes; recover (g, tx); top-2 insert.
#pragma unroll
    for (int mt = 0; mt < 4; ++mt)
#pragma unroll
        for (int r = 0; r < 4; ++r) {
            const int sl = mt * 4 + r;
            unsigned k = best[sl];
#pragma unroll
            for (int off = 8; off; off >>= 1) {
                const unsigned o = (unsigned)__shfl_xor((int)k, off, 16);
                k = o < k ? o : k;
            }
            const ull bal = __ballot(best[sl] == k);
            const unsigned grp = (unsigned)((bal >> (quad * 16)) & 0xFFFFull);
            const int wtx = __ffs((int)grp) - 1;
            const unsigned n = (unsigned)((sg0 + (int)(k & 63u)) * 16 + wtx);
            if (tx == 0) {
                const int row = qb0 + mt * 16 + quad * 4 + r;
                const ull key64 = ((ull)k << 32) | n;
                const ull old = atomicMin(&keys1[row], key64);
                const ull loser = (key64 < old) ? old : key64;
                if (loser != ~0ull) atomicMin(&keys2[row], loser);
            }
        }
}

// ---------------- Kernel C: exact fp32 rescore of approx top-2 ----------------
__global__ __launch_bounds__(256) void rescore_kernel(const float* __restrict__ q,
                                                      const float* __restrict__ v,
                                                      const ull* __restrict__ keys1,
                                                      const ull* __restrict__ keys2,
                                                      int* __restrict__ out) {
    const int qi   = blockIdx.x * 4 + (threadIdx.x >> 6);
    const int lane = threadIdx.x & 63;
    const float4 qv = *(const float4*)(q + (size_t)qi * D + lane * 4);
    ull best = ~0ull;
    ull cand[2];
    cand[0] = keys1[qi];
    cand[1] = keys2[qi];
#pragma unroll
    for (int c = 0; c < 2; ++c) {
        if (cand[c] == ~0ull) continue;
        const unsigned idx = (unsigned)cand[c];
        const float4 vv = *(const float4*)(v + (size_t)idx * D + lane * 4);
        float s1 = vv.x * vv.x + vv.y * vv.y + vv.z * vv.z + vv.w * vv.w;   // ||v||^2
        float s2 = qv.x * vv.x + qv.y * vv.y + qv.z * vv.z + qv.w * vv.w;   // q.v
#pragma unroll
        for (int off = 32; off; off >>= 1) {
            s1 += __shfl_xor(s1, off, 64);
            s2 += __shfl_xor(s2, off, 64);
        }
        const float dist = fmaf(-2.0f, s2, s1);   // exact fp32 (sans ||q||^2)
        const ull key = pack_key(dist, idx);
        best = best < key ? best : key;
    }
    if (lane == 0) out[qi] = (int)(unsigned)(best & 0xFFFFFFFFull);
}

extern "C" void kernel_launch(void* const* d_in, const int* in_sizes, int n_in,
                              void* d_out, int out_size, void* d_ws, size_t ws_size,
                              hipStream_t stream) {
    const float* q = (const float*)d_in[0];
    const float* v = (const float*)d_in[1];
    int* out = (int*)d_out;

    ull* keys1 = (ull*)d_ws;                 // 32KB workspace total (reset cost ~0)
    ull* keys2 = keys1 + M;

    hipMemsetAsync(d_ws, 0xFF, (size_t)2 * M * sizeof(ull), stream);

    dist_argmin_fused<<<(M / 256) * NSLICE, 256, 0, stream>>>(q, v, keys1, keys2);

    rescore_kernel<<<M / 4, 256, 0, stream>>>(q, v, keys1, keys2, out);
}

// Round 4
// 376.097 us; speedup vs baseline: 1.1379x; 1.0427x over previous
//
#include <hip/hip_runtime.h>
#include <hip/hip_bf16.h>

#define M 2048
#define N 131072
#define D 256

#define SLICE_G 64                     // n-groups (of 16) per slice = 1024 n
#define NSLICE  (N / (SLICE_G * 16))   // 128
#define BIAS    1024.0f                // score = vsq+BIAS-2qv > 0 -> uint-sortable bits

typedef __attribute__((ext_vector_type(8))) _Float16 half8;  // 8 f16 (4 VGPRs)
typedef __attribute__((ext_vector_type(8))) short short8;
typedef __attribute__((ext_vector_type(4))) float f32x4;     // MFMA acc
typedef unsigned long long ull;

__device__ __forceinline__ ull pack_key(float score, unsigned idx) {
    unsigned u = __float_as_uint(score);
    u = (u & 0x80000000u) ? ~u : (u | 0x80000000u);
    return ((ull)u << 32) | idx;
}

// ---------------- Kernel B: FULLY FUSED, 2-tile-deep register staging pipeline -------
// R3 was latency-bound: loads issued 1 phase (~320cyc) before use, but v misses LLC
// (FETCH=94MB/disp) -> ~900cyc HBM latency -> every wave stalled ~600cyc/tile at the
// vmcnt inside stage_store, synchronized by the per-tile barrier. Fix: unroll g-loop
// x2 with TWO named register staging sets (compile-time indexed); loads for tile g+2
// issue while tile g computes and tile g+1 (loaded 2 phases ago, ~750cyc cover) is
// cvt'd + ds_written. Compiler emits counted vmcnt(4) per set. LDS layout unchanged
// from R3 (frag-linear f16, measured 0 bank conflicts).
__global__ __launch_bounds__(256, 2) void dist_argmin_fused(const float* __restrict__ q,
                                                            const float* __restrict__ v,
                                                            ull* __restrict__ keys1,
                                                            ull* __restrict__ keys2) {
    __shared__ short bt[2][8 * 512];       // f16 frag-linear tile, 8KB x 2 (even/odd g)
    __shared__ float vsq_s[2][4][16];      // per-buffer, per-wave row-sumsq partials

    const int tid  = threadIdx.x;
    const int lane = tid & 63;
    const int w    = tid >> 6;
    const int tx   = lane & 15;
    const int quad = (lane >> 4) & 3;

    // XCD swizzle: 1024 blocks; lb%8 = XCD; each XCD covers its own 16 slices
    const int lb    = blockIdx.x;
    const int xcd   = lb & 7;
    const int s_    = lb >> 3;              // 0..127 within XCD
    const int slice = xcd * 16 + (s_ >> 3);
    const int qblk  = s_ & 7;

    const int qb0 = qblk * 256 + w * 64;    // wave's first q-row (64 rows)
    const int sg0 = slice * SLICE_G;

    // Prologue: A-frags direct from fp32 q (L2-hot), cvt in regs (128 regs)
    half8 aq[4][8];
#pragma unroll
    for (int mt = 0; mt < 4; ++mt) {
        const float* qrow = q + (size_t)(qb0 + mt * 16 + tx) * 256 + quad * 8;
#pragma unroll
        for (int c = 0; c < 8; ++c) {
            const float4 f0 = *(const float4*)(qrow + c * 32);
            const float4 f1 = *(const float4*)(qrow + c * 32 + 4);
            half8 hh;
            hh[0] = (_Float16)f0.x; hh[1] = (_Float16)f0.y;
            hh[2] = (_Float16)f0.z; hh[3] = (_Float16)f0.w;
            hh[4] = (_Float16)f1.x; hh[5] = (_Float16)f1.y;
            hh[6] = (_Float16)f1.z; hh[7] = (_Float16)f1.w;
            aq[mt][c] = hh;
        }
    }

    unsigned best[16];
#pragma unroll
    for (int i = 0; i < 16; ++i) best[i] = 0xFFFFFFFFu;

    // wave stages chunks c0=w, c1=w+4; lane covers row tx, k=c*32+quad*8..+7
    const int c0 = w, c1 = w + 4;
    const float* vtile = v + ((size_t)sg0 * 16 + tx) * 256 + quad * 8;

    // Two named staging sets (2 tiles in flight; compile-time indexed, no scratch)
    float4 a00, a01, a10, a11;              // set A
    float4 b00, b01, b10, b11;              // set B

    auto loadS = [&](float4& s00, float4& s01, float4& s10, float4& s11, int g) {
        const float* p = vtile + (size_t)g * 4096;
        s00 = *(const float4*)(p + c0 * 32);
        s01 = *(const float4*)(p + c0 * 32 + 4);
        s10 = *(const float4*)(p + c1 * 32);
        s11 = *(const float4*)(p + c1 * 32 + 4);
    };
    auto storeS = [&](const float4& s00, const float4& s01,
                      const float4& s10, const float4& s11, int pb) {
        float s = s00.x * s00.x + s00.y * s00.y + s00.z * s00.z + s00.w * s00.w;
        s = fmaf(s01.x, s01.x, s); s = fmaf(s01.y, s01.y, s);
        s = fmaf(s01.z, s01.z, s); s = fmaf(s01.w, s01.w, s);
        s = fmaf(s10.x, s10.x, s); s = fmaf(s10.y, s10.y, s);
        s = fmaf(s10.z, s10.z, s); s = fmaf(s10.w, s10.w, s);
        s = fmaf(s11.x, s11.x, s); s = fmaf(s11.y, s11.y, s);
        s = fmaf(s11.z, s11.z, s); s = fmaf(s11.w, s11.w, s);
        half8 h0, h1;
        h0[0] = (_Float16)s00.x; h0[1] = (_Float16)s00.y;
        h0[2] = (_Float16)s00.z; h0[3] = (_Float16)s00.w;
        h0[4] = (_Float16)s01.x; h0[5] = (_Float16)s01.y;
        h0[6] = (_Float16)s01.z; h0[7] = (_Float16)s01.w;
        h1[0] = (_Float16)s10.x; h1[1] = (_Float16)s10.y;
        h1[2] = (_Float16)s10.z; h1[3] = (_Float16)s10.w;
        h1[4] = (_Float16)s11.x; h1[5] = (_Float16)s11.y;
        h1[6] = (_Float16)s11.z; h1[7] = (_Float16)s11.w;
        *(short8*)&bt[pb][c0 * 512 + lane * 8] = *(short8*)&h0;   // linear 1KB, 0 conflicts
        *(short8*)&bt[pb][c1 * 512 + lane * 8] = *(short8*)&h1;
        s += __shfl_xor(s, 16, 64);
        s += __shfl_xor(s, 32, 64);          // row-tx sumsq over this wave's 2 chunks
        if (lane < 16) vsq_s[pb][w][lane] = s;
    };

    auto compute = [&](int pb, int g) {
        const float vsqr = vsq_s[pb][0][tx] + vsq_s[pb][1][tx]
                         + vsq_s[pb][2][tx] + vsq_s[pb][3][tx] + BIAS;
        f32x4 acc[4];
#pragma unroll
        for (int i = 0; i < 4; ++i) acc[i] = (f32x4){0.f, 0.f, 0.f, 0.f};
        __builtin_amdgcn_s_setprio(1);
#pragma unroll
        for (int c = 0; c < 8; ++c) {
            const half8 b = *(const half8*)&bt[pb][c * 512 + lane * 8];
#pragma unroll
            for (int mt = 0; mt < 4; ++mt)
                acc[mt] = __builtin_amdgcn_mfma_f32_16x16x32_f16(aq[mt][c], b, acc[mt], 0, 0, 0);
        }
        __builtin_amdgcn_s_setprio(0);
#pragma unroll
        for (int mt = 0; mt < 4; ++mt)
#pragma unroll
            for (int r = 0; r < 4; ++r) {
                const float sc = fmaf(-2.f, acc[mt][r], vsqr);
                const unsigned key = (__float_as_uint(sc) & 0xFFFFFFC0u) | (unsigned)g;
                const int sl = mt * 4 + r;
                best[sl] = key < best[sl] ? key : best[sl];
            }
    };

    // Pipeline prologue: tiles 0 (set A) and 1 (set B) in flight; publish tile 0
    loadS(a00, a01, a10, a11, 0);
    loadS(b00, b01, b10, b11, 1);
    storeS(a00, a01, a10, a11, 0);          // waits only set A (vmcnt(4))
    __syncthreads();                        // bt[0] ready

    for (int g = 0; g < SLICE_G; g += 2) {
        // even half-step: compute tile g (bt[0]); tile g+1 in set B; load g+2 -> set A
        if (g + 2 < SLICE_G) loadS(a00, a01, a10, a11, g + 2);
        compute(0, g);
        storeS(b00, b01, b10, b11, 1);      // tile g+1 (loaded 2 phases ago)
        __syncthreads();                    // bt[1] ready
        // odd half-step: compute tile g+1 (bt[1]); load g+3 -> set B
        if (g + 3 < SLICE_G) loadS(b00, b01, b10, b11, g + 3);
        compute(1, g + 1);
        if (g + 2 < SLICE_G) storeS(a00, a01, a10, a11, 0);   // tile g+2
        __syncthreads();                    // bt[0] ready
    }

    // Epilogue: per slot, min across 16 tx lanes; recover (g, tx); top-2 insert.
#pragma unroll
    for (int mt = 0; mt < 4; ++mt)
#pragma unroll
        for (int r = 0; r < 4; ++r) {
            const int sl = mt * 4 + r;
            unsigned k = best[sl];
#pragma unroll
            for (int off = 8; off; off >>= 1) {
                const unsigned o = (unsigned)__shfl_xor((int)k, off, 16);
                k = o < k ? o : k;
            }
            const ull bal = __ballot(best[sl] == k);
            const unsigned grp = (unsigned)((bal >> (quad * 16)) & 0xFFFFull);
            const int wtx = __ffs((int)grp) - 1;
            const unsigned n = (unsigned)((sg0 + (int)(k & 63u)) * 16 + wtx);
            if (tx == 0) {
                const int row = qb0 + mt * 16 + quad * 4 + r;
                const ull key64 = ((ull)k << 32) | n;
                const ull old = atomicMin(&keys1[row], key64);
                const ull loser = (key64 < old) ? old : key64;
                if (loser != ~0ull) atomicMin(&keys2[row], loser);
            }
        }
}

// ---------------- Kernel C: exact fp32 rescore of approx top-2 ----------------
__global__ __launch_bounds__(256) void rescore_kernel(const float* __restrict__ q,
                                                      const float* __restrict__ v,
                                                      const ull* __restrict__ keys1,
                                                      const ull* __restrict__ keys2,
                                                      int* __restrict__ out) {
    const int qi   = blockIdx.x * 4 + (threadIdx.x >> 6);
    const int lane = threadIdx.x & 63;
    const float4 qv = *(const float4*)(q + (size_t)qi * D + lane * 4);
    ull best = ~0ull;
    ull cand[2];
    cand[0] = keys1[qi];
    cand[1] = keys2[qi];
#pragma unroll
    for (int c = 0; c < 2; ++c) {
        if (cand[c] == ~0ull) continue;
        const unsigned idx = (unsigned)cand[c];
        const float4 vv = *(const float4*)(v + (size_t)idx * D + lane * 4);
        float s1 = vv.x * vv.x + vv.y * vv.y + vv.z * vv.z + vv.w * vv.w;   // ||v||^2
        float s2 = qv.x * vv.x + qv.y * vv.y + qv.z * vv.z + qv.w * vv.w;   // q.v
#pragma unroll
        for (int off = 32; off; off >>= 1) {
            s1 += __shfl_xor(s1, off, 64);
            s2 += __shfl_xor(s2, off, 64);
        }
        const float dist = fmaf(-2.0f, s2, s1);   // exact fp32 (sans ||q||^2)
        const ull key = pack_key(dist, idx);
        best = best < key ? best : key;
    }
    if (lane == 0) out[qi] = (int)(unsigned)(best & 0xFFFFFFFFull);
}

extern "C" void kernel_launch(void* const* d_in, const int* in_sizes, int n_in,
                              void* d_out, int out_size, void* d_ws, size_t ws_size,
                              hipStream_t stream) {
    const float* q = (const float*)d_in[0];
    const float* v = (const float*)d_in[1];
    int* out = (int*)d_out;

    ull* keys1 = (ull*)d_ws;                 // 32KB workspace total
    ull* keys2 = keys1 + M;

    hipMemsetAsync(d_ws, 0xFF, (size_t)2 * M * sizeof(ull), stream);

    dist_argmin_fused<<<(M / 256) * NSLICE, 256, 0, stream>>>(q, v, keys1, keys2);

    rescore_kernel<<<M / 4, 256, 0, stream>>>(q, v, keys1, keys2, out);
}